// Round 6
// baseline (121082.568 us; speedup 1.0000x reference)
//
#include <hip/hip_runtime.h>
#include <hip/hip_bf16.h>

// Problem constants
constexpr int kN = 8192;
constexpr int kF = 256;
constexpr int kH = 512;
constexpr int kL = 512;
constexpr int kE = kN * 4;           // 32768 edges

using ull = unsigned long long;

__device__ __forceinline__ float sigm(float x) { return 1.f / (1.f + __expf(-x)); }

__device__ __forceinline__ float4 ld_bf4(const __hip_bfloat16* p) {
    uint2 u = *(const uint2*)p;
    float4 r;
    r.x = __uint_as_float(u.x << 16);
    r.y = __uint_as_float(u.x & 0xffff0000u);
    r.z = __uint_as_float(u.y << 16);
    r.w = __uint_as_float(u.y & 0xffff0000u);
    return r;
}

// stamped 8-byte pair: low = float bits, high = stamp (step+1)
// uni==true  : all participants verified same-XCD -> plain volatile 8B ops
//              (stay in the XCD L2, which is the intra-XCD coherence point)
// uni==false : agent-scope relaxed atomics (sc1/MALL path, any placement)
__device__ __forceinline__ void st_pair(ull* p, float v, unsigned stamp, bool uni) {
    ull u = ((ull)stamp << 32) | (ull)__float_as_uint(v);
    if (uni) *(volatile ull*)p = u;
    else __hip_atomic_store(p, u, __ATOMIC_RELAXED, __HIP_MEMORY_SCOPE_AGENT);
}
__device__ __forceinline__ ull ld_pair(const ull* p, bool uni) {
    if (uni) return *(const volatile ull*)p;
    return __hip_atomic_load(p, __ATOMIC_RELAXED, __HIP_MEMORY_SCOPE_AGENT);
}

// ---------------------------------------------------------------------------
__global__ void k_init(float* __restrict__ out, const float* __restrict__ bdo,
                       ull* __restrict__ hpay, ull* __restrict__ zpay,
                       int* __restrict__ claims, int* __restrict__ xcc_tab) {
    int idx = blockIdx.x * 256 + threadIdx.x;
    if (idx < kE) out[idx] = bdo[0];
    if (idx < 2 * 2 * 4 * kH) hpay[idx] = 0ull;
    if (idx < 2 * 2 * 32 * 256) zpay[idx] = 0ull;
    if (idx < 2) claims[idx] = 0;
    if (idx < 64) xcc_tab[idx] = 0;
}

__global__ void k_zero(float* __restrict__ out) {
    int idx = blockIdx.x * 256 + threadIdx.x;
    if (idx < kE) out[idx] = 0.f;
}

// ---------------------------------------------------------------------------
// Recurrent kernel: 512 candidate blocks; 32 working blocks per direction,
// claimed by XCD (XCD0 -> fwd, XCD1 -> bwd; other XCDs late fallback).
// Placement is then VERIFIED via an xcc table; if a direction's 32 blocks all
// measured the same XCC, the exchange runs on L2-coherent volatile ops.
// Block b owns h-dims [b*16, b*16+16) -> 64 gate rows (Whh slice in VGPRs).
// ---------------------------------------------------------------------------
__global__ __launch_bounds__(256, 1) void k_recur(
    const float* __restrict__ edges,
    const float* __restrict__ Wih_f, const float* __restrict__ Whh_f, const float* __restrict__ b_f,
    const float* __restrict__ Wih_b, const float* __restrict__ Whh_b, const float* __restrict__ b_b,
    const float* __restrict__ Wa, const float* __restrict__ ba,
    const float* __restrict__ Wao, const float* __restrict__ bao,
    __hip_bfloat16* __restrict__ arc_f, __hip_bfloat16* __restrict__ arc_b,
    ull* __restrict__ hpay, ull* __restrict__ zpay,
    int* __restrict__ claims, int* __restrict__ xcc_tab) {

    // ---- XCD-affine slot claim ----
    __shared__ int s_slot, s_uni;
    if (threadIdx.x == 0) {
        // s_getreg(HW_REG_XCC_ID): simm16 = (size-1)<<11 | offset<<6 | id(20)
        unsigned xcc = (unsigned)__builtin_amdgcn_s_getreg((31 << 11) | (0 << 6) | 20) & 15u;
        int slot = -1;
        if (xcc <= 1) {
            int c = atomicAdd(&claims[xcc], 1);
            if (c < 32) slot = (int)xcc * 32 + c;
        } else {
            // wrong XCD: wait ~100us, then fill any unfilled slots (robust fallback)
            for (int sl = 0; sl < 64; sl++) __builtin_amdgcn_s_sleep(64);
            for (int dd = 0; dd < 2 && slot < 0; dd++) {
                if (__hip_atomic_load(&claims[dd], __ATOMIC_RELAXED,
                                      __HIP_MEMORY_SCOPE_AGENT) < 32) {
                    int c = atomicAdd(&claims[dd], 1);
                    if (c < 32) slot = dd * 32 + c;
                }
            }
        }
        s_slot = slot;
        if (slot >= 0) {
            __hip_atomic_store(&xcc_tab[slot], 0x100 | (int)xcc,
                               __ATOMIC_RELAXED, __HIP_MEMORY_SCOPE_AGENT);
            // verify: all 32 slots of this direction on MY xcd?
            const int base = (slot >> 5) * 32;
            int u2 = 1;
            for (int k2 = 0; k2 < 32; k2++) {
                int v;
                do { v = __hip_atomic_load(&xcc_tab[base + k2], __ATOMIC_RELAXED,
                                           __HIP_MEMORY_SCOPE_AGENT); } while (!(v & 0x100));
                u2 &= ((v & 0xff) == (int)xcc) ? 1 : 0;
            }
            s_uni = u2;
        }
    }
    __syncthreads();
    const int slot = s_slot;
    if (slot < 0) return;
    const bool uni = (s_uni != 0);
    const int dir = slot >> 5;
    const int b   = slot & 31;

    const float* __restrict__ Whh = dir ? Whh_b : Whh_f;
    const float* __restrict__ Wih = dir ? Wih_b : Wih_f;
    const float* __restrict__ bia = dir ? b_b  : b_f;
    __hip_bfloat16* __restrict__ arc = dir ? arc_b : arc_f;
    const int tid = threadIdx.x;

    // matvec roles: 64 gate rows x 4-way K split
    const int jl = tid >> 2, ks = tid & 3;
    const int Jg = (jl >> 4) * kH + b * 16 + (jl & 15);
    // gate / xproj / z roles: wave = arc, lane = gate row (or attention unit)
    const int d_g = tid >> 6, jl2 = tid & 63;
    const int Jg2 = (jl2 >> 4) * kH + b * 16 + (jl2 & 15);
    const int a_id = jl2;

    float w[128];
    {
        const float* wr = Whh + (size_t)Jg * kH + ks * 128;
        #pragma unroll
        for (int kk = 0; kk < 128; kk++) w[kk] = wr[kk];
    }
    float wih[64];
    {
        const float* wr = Wih + (size_t)Jg2 * kF + d_g * 64;
        #pragma unroll
        for (int kk = 0; kk < 64; kk++) wih[kk] = wr[kk];
    }
    const float biasR = bia[Jg2];
    const float baR   = ba[a_id];
    const float WaoR  = Wao[a_id];
    const float baoR  = bao[0];
    const float wax0  = Wa[(size_t)a_id * 515 + 512];
    const float wax1  = Wa[(size_t)a_id * 515 + 513];
    const float wax2  = Wa[(size_t)a_id * 515 + 514];

    // hprev padded: 4 chunks of 132 floats (banks offset 4 per chunk -> no conflict)
    __shared__ __align__(16) float hprev_p[4 * 132];
    __shared__ float Mh[4][64];
    __shared__ float cring[4][16];
    __shared__ float harcl[4][16];
    __shared__ float carcl[4][16];
    __shared__ float logit_l[4];
    __shared__ float WaS[64][17];
    __shared__ float xpl[4][64];         // per-arc gate-x projection (this node)
    __shared__ __align__(16) float x_s[4][256];
    __shared__ float xpart[4][4][64];

    for (int l2 = tid; l2 < 4 * 132; l2 += 256) hprev_p[l2] = 0.f;
    Mh[tid >> 6][tid & 63] = 0.f;
    if (tid < 64) cring[tid >> 4][tid & 15] = 0.f;
    for (int l2 = tid; l2 < 1024; l2 += 256)
        WaS[l2 >> 4][l2 & 15] = Wa[(size_t)(l2 >> 4) * 515 + b * 16 + (l2 & 15)];
    __syncthreads();

// issue the edge-row load for node nn (block-uniform)
#define XLOAD(nn, XV) do {                                                    \
        int row_;                                                             \
        if (dir == 0) row_ = (nn) * 4 + d_g;                                  \
        else { row_ = ((nn) + 1 + d_g) * 4 + d_g;                             \
               if (row_ > kE - 1) row_ = kE - 1; }                            \
        XV = *(const float4*)(edges + (size_t)row_ * kF + 4 * jl2);           \
    } while (0)

// finish xproj from a prefetched edge vector; writes xpl (next node), returns zx
#define XFIN(XV, ZXOUT) do {                                                  \
        *(float4*)(&x_s[d_g][4 * jl2]) = XV;                                  \
        __syncthreads();                                                      \
        float p0_ = 0.f, p1_ = 0.f, p2_ = 0.f, p3_ = 0.f;                     \
        _Pragma("unroll")                                                     \
        for (int k4_ = 0; k4_ < 16; k4_++) {                                  \
            float4 a0_ = *(const float4*)&x_s[0][d_g * 64 + k4_ * 4];         \
            float4 a1_ = *(const float4*)&x_s[1][d_g * 64 + k4_ * 4];         \
            float4 a2_ = *(const float4*)&x_s[2][d_g * 64 + k4_ * 4];         \
            float4 a3_ = *(const float4*)&x_s[3][d_g * 64 + k4_ * 4];         \
            float w0_ = wih[k4_*4], w1_ = wih[k4_*4+1];                       \
            float w2_ = wih[k4_*4+2], w3_ = wih[k4_*4+3];                     \
            p0_ += w0_*a0_.x + w1_*a0_.y + w2_*a0_.z + w3_*a0_.w;             \
            p1_ += w0_*a1_.x + w1_*a1_.y + w2_*a1_.z + w3_*a1_.w;             \
            p2_ += w0_*a2_.x + w1_*a2_.y + w2_*a2_.z + w3_*a2_.w;             \
            p3_ += w0_*a3_.x + w1_*a3_.y + w2_*a3_.z + w3_*a3_.w;             \
        }                                                                     \
        xpart[d_g][0][jl2] = p0_; xpart[d_g][1][jl2] = p1_;                   \
        xpart[d_g][2][jl2] = p2_; xpart[d_g][3][jl2] = p3_;                   \
        __syncthreads();                                                      \
        xpl[d_g][jl2] = biasR + xpart[0][d_g][jl2] + xpart[1][d_g][jl2]       \
                              + xpart[2][d_g][jl2] + xpart[3][d_g][jl2];      \
        ZXOUT = baR + wax0 * x_s[d_g][0] + wax1 * x_s[d_g][1]                 \
                    + wax2 * x_s[d_g][2];                                     \
    } while (0)

    const int i0 = dir ? kN - 1 : 0;
    float zxv;
    {
        float4 xv0;
        XLOAD(i0, xv0);
        XFIN(xv0, zxv);
    }
    __syncthreads();   // xpl(i0) visible before step 0's cell

    for (int t = 0; t < kN; t++) {
        const int i = dir ? kN - 1 - t : t;
        const unsigned stamp = (unsigned)(t + 1);
        const int par = t & 1;

        // ---- prefetch next step's edge row (latency overlaps phases A/B) ----
        float4 xv_n;
        {
            const int nn = (t + 1 < kN) ? (dir ? i - 1 : i + 1) : i;
            XLOAD(nn, xv_n);
        }

        // ---- A: M[iprev] = hprev . Whh^T (own 64 rows) ----
        float acc = 0.f;
        {
            const float* hp = &hprev_p[ks * 132];
            #pragma unroll
            for (int kk = 0; kk < 128; kk += 4) {
                float4 hv = *(const float4*)(hp + kk);
                acc += w[kk] * hv.x + w[kk+1] * hv.y + w[kk+2] * hv.z + w[kk+3] * hv.w;
            }
        }
        acc += __shfl_xor(acc, 1);
        acc += __shfl_xor(acc, 2);
        const int iprev = dir ? i + 1 : i - 1;
        if (ks == 0) Mh[iprev & 3][jl] = acc;
        __syncthreads();

        // ---- B: per-wave LSTM cell (wave = arc), publish h + z; no barrier ----
        const int pp = dir ? i + 1 + d_g : i - 1 - d_g;
        const bool v3 = dir ? (pp < kN) : (pp >= 0);
        if (jl2 < 16) {
            const int s3 = jl2;
            float gi = xpl[d_g][s3]      + Mh[pp & 3][s3];
            float gf = xpl[d_g][16 + s3] + Mh[pp & 3][16 + s3];
            float gg = xpl[d_g][32 + s3] + Mh[pp & 3][32 + s3];
            float go = xpl[d_g][48 + s3] + Mh[pp & 3][48 + s3];
            float cp = cring[pp & 3][s3];
            float c = sigm(gf) * cp + sigm(gi) * tanhf(gg);
            float h = sigm(go) * tanhf(c);
            float hm = v3 ? h : 0.f, cm = v3 ? c : 0.f;
            harcl[d_g][s3] = hm; carcl[d_g][s3] = cm;
            arc[((size_t)i * 4 + d_g) * kH + b * 16 + s3] = __float2bfloat16(hm);
            st_pair(hpay + (((dir * 2 + par) * 4 + d_g) << 9) + b * 16 + s3, hm, stamp, uni);
        }
        {   // z partial over own 16 h-dims (intra-wave harcl dep, no barrier)
            float zp = 0.f;
            #pragma unroll
            for (int ss = 0; ss < 16; ss++) zp += WaS[a_id][ss] * harcl[d_g][ss];
            st_pair(zpay + (((dir * 2 + par) * 32 + b) << 8) + tid, zp, stamp, uni);
        }

        // ---- C: next node's input projection (overlaps publish visibility) ----
        float zx_n;
        XFIN(xv_n, zx_n);

        // ---- E: batched stamped loads (z + h) ----
        const ull* zb = zpay + (((size_t)(dir * 2 + par) * 32) << 8) + tid;
        ull zv_[32];
        #pragma unroll
        for (int bb = 0; bb < 32; bb++) zv_[bb] = ld_pair(zb + ((size_t)bb << 8), uni);
        const ull* hb = hpay + (((size_t)(dir * 2 + par) * 4) << 9);
        ull hv_[8];
        #pragma unroll
        for (int dd = 0; dd < 4; dd++) {
            hv_[2*dd]   = ld_pair(hb + (dd << 9) + 2 * tid, uni);
            hv_[2*dd+1] = ld_pair(hb + (dd << 9) + 2 * tid + 1, uni);
        }

        // resolve z: batched sweeps (all unresolved re-issued in flight)
        for (;;) {
            bool ok = true;
            #pragma unroll
            for (int bb = 0; bb < 32; bb++)
                ok &= ((unsigned)(zv_[bb] >> 32) == stamp);
            if (ok) break;
            #pragma unroll
            for (int bb = 0; bb < 32; bb++)
                if ((unsigned)(zv_[bb] >> 32) != stamp)
                    zv_[bb] = ld_pair(zb + ((size_t)bb << 8), uni);
        }
        float zsum = 0.f;
        #pragma unroll
        for (int bb = 0; bb < 32; bb++) zsum += __uint_as_float((unsigned)zv_[bb]);

        // resolve h: batched sweeps
        for (;;) {
            bool ok = true;
            #pragma unroll
            for (int q = 0; q < 8; q++)
                ok &= ((unsigned)(hv_[q] >> 32) == stamp);
            if (ok) break;
            #pragma unroll
            for (int dd = 0; dd < 4; dd++) {
                if ((unsigned)(hv_[2*dd]   >> 32) != stamp) hv_[2*dd]   = ld_pair(hb + (dd << 9) + 2 * tid, uni);
                if ((unsigned)(hv_[2*dd+1] >> 32) != stamp) hv_[2*dd+1] = ld_pair(hb + (dd << 9) + 2 * tid + 1, uni);
            }
        }

        float zv = fmaxf(zsum + zxv, 0.f);
        float lv = WaoR * zv;
        #pragma unroll
        for (int o2 = 1; o2 < 64; o2 <<= 1) lv += __shfl_xor(lv, o2);
        if (a_id == 0) {
            logit_l[d_g] = v3 ? tanhf(lv + baoR) : -1e9f;
        }
        __syncthreads();

        float l0 = logit_l[0], l1 = logit_l[1], l2 = logit_l[2], l3 = logit_l[3];
        float mx = fmaxf(fmaxf(l0, l1), fmaxf(l2, l3));
        float e0 = __expf(l0 - mx), e1 = __expf(l1 - mx);
        float e2 = __expf(l2 - mx), e3 = __expf(l3 - mx);
        float inv = 1.f / (e0 + e1 + e2 + e3);
        float wg[4] = { e0 * inv, e1 * inv, e2 * inv, e3 * inv };

        float hn0 = 0.f, hn1 = 0.f;
        #pragma unroll
        for (int dd = 0; dd < 4; dd++) {
            hn0 += wg[dd] * __uint_as_float((unsigned)hv_[2*dd]);
            hn1 += wg[dd] * __uint_as_float((unsigned)hv_[2*dd+1]);
        }
        {
            const int g = 2 * tid;
            const int ch = g >> 7, wi = g & 127;
            hprev_p[ch * 132 + wi]     = hn0;
            hprev_p[ch * 132 + wi + 1] = hn1;
        }
        if (tid < 16) {
            float cn = wg[0] * carcl[0][tid] + wg[1] * carcl[1][tid]
                     + wg[2] * carcl[2][tid] + wg[3] * carcl[3][tid];
            cring[i & 3][tid] = cn;
        }
        __syncthreads();

        zxv = zx_n;
    }
#undef XLOAD
#undef XFIN
}

// ---------------------------------------------------------------------------
// decoder: out[e] += sum_l Wdo[l] * relu(bd[l] + sum_k Wd[l,k] feat[e,k])
// ---------------------------------------------------------------------------
__global__ __launch_bounds__(256) void k_dec(
    const __hip_bfloat16* __restrict__ arc_f, const __hip_bfloat16* __restrict__ arc_b,
    const float* __restrict__ Wd, const float* __restrict__ bd,
    const float* __restrict__ Wdo, float* __restrict__ out) {
    const int e0 = blockIdx.x * 128;
    const int l0 = blockIdx.y * 128;
    __shared__ __align__(16) float As[8][128];
    __shared__ __align__(16) float Bs[8][128];
    const int tid = threadIdx.x;
    const int tx = tid & 15, ty = tid >> 4;
    const int lr = tid & 127, kq = tid >> 7;

    const int e = e0 + lr;
    const int j = e >> 2, d = e & 3;
    const int jb = j - 1 - d;
    const __hip_bfloat16* frow  = arc_f + (size_t)e * kH;
    const __hip_bfloat16* brow2 = (jb >= 0) ? (arc_b + ((size_t)jb * 4 + d) * kH) : nullptr;
    const float* wrow = Wd + (size_t)(l0 + lr) * (2 * kH);

    float acc[8][8] = {};
    for (int k0 = 0; k0 < 2 * kH; k0 += 8) {
        const int kk = k0 + kq * 4;
        float4 av4;
        if (kk < kH) av4 = ld_bf4(frow + kk);
        else if (brow2) av4 = ld_bf4(brow2 + (kk - kH));
        else av4 = make_float4(0.f, 0.f, 0.f, 0.f);
        float4 bv4 = *(const float4*)(wrow + kk);
        __syncthreads();
        As[kq*4+0][lr] = av4.x; As[kq*4+1][lr] = av4.y;
        As[kq*4+2][lr] = av4.z; As[kq*4+3][lr] = av4.w;
        Bs[kq*4+0][lr] = bv4.x; Bs[kq*4+1][lr] = bv4.y;
        Bs[kq*4+2][lr] = bv4.z; Bs[kq*4+3][lr] = bv4.w;
        __syncthreads();
        #pragma unroll
        for (int kt = 0; kt < 8; kt++) {
            __align__(16) float a0[8], b0[8];
            *(float4*)&a0[0] = *(const float4*)&As[kt][ty*8];
            *(float4*)&a0[4] = *(const float4*)&As[kt][ty*8+4];
            *(float4*)&b0[0] = *(const float4*)&Bs[kt][tx*8];
            *(float4*)&b0[4] = *(const float4*)&Bs[kt][tx*8+4];
            #pragma unroll
            for (int mi = 0; mi < 8; mi++)
                #pragma unroll
                for (int ni = 0; ni < 8; ni++)
                    acc[mi][ni] += a0[mi] * b0[ni];
        }
    }
    #pragma unroll
    for (int mi = 0; mi < 8; mi++) {
        float sacc = 0.f;
        #pragma unroll
        for (int ni = 0; ni < 8; ni++) {
            int l = l0 + tx * 8 + ni;
            sacc += Wdo[l] * fmaxf(acc[mi][ni] + bd[l], 0.f);
        }
        sacc += __shfl_xor(sacc, 1);
        sacc += __shfl_xor(sacc, 2);
        sacc += __shfl_xor(sacc, 4);
        sacc += __shfl_xor(sacc, 8);
        if (tx == 0) atomicAdd(out + e0 + ty * 8 + mi, sacc);
    }
}

// ---------------------------------------------------------------------------
extern "C" void kernel_launch(void* const* d_in, const int* in_sizes, int n_in,
                              void* d_out, int out_size, void* d_ws, size_t ws_size,
                              hipStream_t stream) {
    const float* edges = (const float*)d_in[0];
    const float* Wih_f = (const float*)d_in[1];
    const float* Whh_f = (const float*)d_in[2];
    const float* b_f   = (const float*)d_in[3];
    const float* Wih_b = (const float*)d_in[4];
    const float* Whh_b = (const float*)d_in[5];
    const float* b_b   = (const float*)d_in[6];
    const float* Wa    = (const float*)d_in[7];
    const float* ba    = (const float*)d_in[8];
    const float* Wao   = (const float*)d_in[9];
    const float* bao   = (const float*)d_in[10];
    const float* Wd    = (const float*)d_in[11];
    const float* bd    = (const float*)d_in[12];
    const float* Wdo   = (const float*)d_in[13];
    const float* bdo   = (const float*)d_in[14];
    float* out = (float*)d_out;

    char* ws = (char*)d_ws;
    size_t off = 0;
    __hip_bfloat16* arc_f = (__hip_bfloat16*)(ws + off); off += (size_t)kE * kH * 2;  // 32 MB
    __hip_bfloat16* arc_b = (__hip_bfloat16*)(ws + off); off += (size_t)kE * kH * 2;  // 32 MB
    ull* hpay = (ull*)(ws + off); off += (size_t)2 * 2 * 4 * kH * 8;                  // 64 KB
    ull* zpay = (ull*)(ws + off); off += (size_t)2 * 2 * 32 * 256 * 8;                // 256 KB
    int* claims = (int*)(ws + off); off += 64;
    int* xcc_tab = (int*)(ws + off); off += 256;

    if (ws_size < off) {
        hipLaunchKernelGGL(k_zero, dim3((kE + 255) / 256), dim3(256), 0, stream, out);
        return;
    }

    hipLaunchKernelGGL(k_init, dim3(128), dim3(256), 0, stream,
                       out, bdo, hpay, zpay, claims, xcc_tab);
    hipLaunchKernelGGL(k_recur, dim3(512), dim3(256), 0, stream,
                       edges, Wih_f, Whh_f, b_f, Wih_b, Whh_b, b_b,
                       Wa, ba, Wao, bao, arc_f, arc_b, hpay, zpay, claims, xcc_tab);
    hipLaunchKernelGGL(k_dec, dim3(kE / 128, kL / 128), dim3(256), 0, stream,
                       arc_f, arc_b, Wd, bd, Wdo, out);
}

// Round 7
// 75559.192 us; speedup vs baseline: 1.6025x; 1.6025x over previous
//
#include <hip/hip_runtime.h>
#include <hip/hip_bf16.h>

// Problem constants
constexpr int kN = 8192;
constexpr int kF = 256;
constexpr int kH = 512;
constexpr int kL = 512;
constexpr int kE = kN * 4;           // 32768 edges

using ull = unsigned long long;

__device__ __forceinline__ float sigm(float x) { return 1.f / (1.f + __expf(-x)); }

__device__ __forceinline__ float4 ld_bf4(const __hip_bfloat16* p) {
    uint2 u = *(const uint2*)p;
    float4 r;
    r.x = __uint_as_float(u.x << 16);
    r.y = __uint_as_float(u.x & 0xffff0000u);
    r.z = __uint_as_float(u.y << 16);
    r.w = __uint_as_float(u.y & 0xffff0000u);
    return r;
}

// stamped 8-byte pair: low = float bits, high = stamp (publish step + 1)
// relaxed agent-scope atomics: pipeline freely (NO volatile: LLVM serializes
// volatile accesses with vmcnt(0) between them -- round-6 3x regression).
__device__ __forceinline__ void st_pair(ull* p, float v, unsigned stamp) {
    ull u = ((ull)stamp << 32) | (ull)__float_as_uint(v);
    __hip_atomic_store(p, u, __ATOMIC_RELAXED, __HIP_MEMORY_SCOPE_AGENT);
}
__device__ __forceinline__ ull ld_pair(const ull* p) {
    return __hip_atomic_load(p, __ATOMIC_RELAXED, __HIP_MEMORY_SCOPE_AGENT);
}

// ---------------------------------------------------------------------------
__global__ void k_init(float* __restrict__ out, const float* __restrict__ bdo,
                       ull* __restrict__ hpay, ull* __restrict__ zpay,
                       int* __restrict__ claims) {
    int idx = blockIdx.x * 256 + threadIdx.x;
    if (idx < kE) out[idx] = bdo[0];
    if (idx < 2 * 2 * 4 * kH) hpay[idx] = 0ull;
    if (idx < 2 * 2 * 32 * 256) zpay[idx] = 0ull;
    if (idx < 2) claims[idx] = 0;
}

__global__ void k_zero(float* __restrict__ out) {
    int idx = blockIdx.x * 256 + threadIdx.x;
    if (idx < kE) out[idx] = 0.f;
}

// ---------------------------------------------------------------------------
// Recurrent kernel, deferred-combination ("Md") schedule:
//   step t consumes node(t-1)'s published h_arc/z (a FULL step of slack for
//   MALL visibility), computes per-arc matvecs Md = h_arc_d . Whh^T, resolves
//   z -> wg(prev), combines M(prev) = sum_d wg_d Md (exact by linearity),
//   then runs node(t)'s LSTM and publishes. h_node is never materialized.
// 512 candidate blocks; 32 working blocks/dir claimed by XCD (XCD0 fwd,
// XCD1 bwd, late fallback otherwise). Block b owns h-dims [b*16,b*16+16).
// ---------------------------------------------------------------------------
__global__ __launch_bounds__(256, 1) void k_recur(
    const float* __restrict__ edges,
    const float* __restrict__ Wih_f, const float* __restrict__ Whh_f, const float* __restrict__ b_f,
    const float* __restrict__ Wih_b, const float* __restrict__ Whh_b, const float* __restrict__ b_b,
    const float* __restrict__ Wa, const float* __restrict__ ba,
    const float* __restrict__ Wao, const float* __restrict__ bao,
    __hip_bfloat16* __restrict__ arc_f, __hip_bfloat16* __restrict__ arc_b,
    ull* __restrict__ hpay, ull* __restrict__ zpay, int* __restrict__ claims) {

    // ---- XCD-affine slot claim ----
    __shared__ int s_slot;
    if (threadIdx.x == 0) {
        unsigned xcc = (unsigned)__builtin_amdgcn_s_getreg((31 << 11) | (0 << 6) | 20) & 15u;
        int slot = -1;
        if (xcc <= 1) {
            int c = atomicAdd(&claims[xcc], 1);
            if (c < 32) slot = (int)xcc * 32 + c;
        } else {
            for (int sl = 0; sl < 64; sl++) __builtin_amdgcn_s_sleep(64);
            for (int dd = 0; dd < 2 && slot < 0; dd++) {
                if (__hip_atomic_load(&claims[dd], __ATOMIC_RELAXED,
                                      __HIP_MEMORY_SCOPE_AGENT) < 32) {
                    int c = atomicAdd(&claims[dd], 1);
                    if (c < 32) slot = dd * 32 + c;
                }
            }
        }
        s_slot = slot;
    }
    __syncthreads();
    const int slot = s_slot;
    if (slot < 0) return;
    const int dir = slot >> 5;
    const int b   = slot & 31;

    const float* __restrict__ Whh = dir ? Whh_b : Whh_f;
    const float* __restrict__ Wih = dir ? Wih_b : Wih_f;
    const float* __restrict__ bia = dir ? b_b  : b_f;
    __hip_bfloat16* __restrict__ arc = dir ? arc_b : arc_f;
    const int tid = threadIdx.x;

    // matvec roles: 64 gate rows x 4-way K split
    const int jl = tid >> 2, ks = tid & 3;
    const int Jg = (jl >> 4) * kH + b * 16 + (jl & 15);
    // gate / xproj / z roles: wave = arc, lane = gate row (or attention unit)
    const int d_g = tid >> 6, jl2 = tid & 63;
    const int Jg2 = (jl2 >> 4) * kH + b * 16 + (jl2 & 15);
    const int a_id = jl2;

    float w[128];
    {
        const float* wr = Whh + (size_t)Jg * kH + ks * 128;
        #pragma unroll
        for (int kk = 0; kk < 128; kk++) w[kk] = wr[kk];
    }
    float wih[64];
    {
        const float* wr = Wih + (size_t)Jg2 * kF + d_g * 64;
        #pragma unroll
        for (int kk = 0; kk < 64; kk++) wih[kk] = wr[kk];
    }
    const float biasR = bia[Jg2];
    const float baR   = ba[a_id];
    const float WaoR  = Wao[a_id];
    const float baoR  = bao[0];
    const float wax0  = Wa[(size_t)a_id * 515 + 512];
    const float wax1  = Wa[(size_t)a_id * 515 + 513];
    const float wax2  = Wa[(size_t)a_id * 515 + 514];

    // ha_p: prev node's full h_arc, 4 arcs x 512 dims, padded 4x132 per arc
    __shared__ __align__(16) float ha_p[4 * 528];
    __shared__ float Mhd[4][64];         // per-arc matvec results (own 64 rows)
    __shared__ float Mh[4][64];          // combined M ring, indexed node&3
    __shared__ float cring[4][16];       // c_node ring, indexed node&3
    __shared__ float harcl[4][16];
    __shared__ float carcl[4][16];       // persists one step (combined next step)
    __shared__ float logit_l[4];
    __shared__ float WaS[64][17];
    __shared__ float xpl[4][64];         // gate-x projection of current node
    __shared__ __align__(16) float x_s[4][256];
    __shared__ float xpart[4][4][64];

    Mh[tid >> 6][tid & 63] = 0.f;
    if (tid < 64) cring[tid >> 4][tid & 15] = 0.f;
    if (tid < 64) { carcl[tid >> 4][tid & 15] = 0.f; harcl[tid >> 4][tid & 15] = 0.f; }
    for (int l2 = tid; l2 < 1024; l2 += 256)
        WaS[l2 >> 4][l2 & 15] = Wa[(size_t)(l2 >> 4) * 515 + b * 16 + (l2 & 15)];
    __syncthreads();

// issue the edge-row load for node nn (block-uniform)
#define XLOAD(nn, XV) do {                                                    \
        int row_;                                                             \
        if (dir == 0) row_ = (nn) * 4 + d_g;                                  \
        else { row_ = ((nn) + 1 + d_g) * 4 + d_g;                             \
               if (row_ > kE - 1) row_ = kE - 1; }                            \
        XV = *(const float4*)(edges + (size_t)row_ * kF + 4 * jl2);           \
    } while (0)

// finish xproj from a prefetched edge vector; writes xpl (that node), returns zx
#define XFIN(XV, ZXOUT) do {                                                  \
        *(float4*)(&x_s[d_g][4 * jl2]) = XV;                                  \
        __syncthreads();                                                      \
        float p0_ = 0.f, p1_ = 0.f, p2_ = 0.f, p3_ = 0.f;                     \
        _Pragma("unroll")                                                     \
        for (int k4_ = 0; k4_ < 16; k4_++) {                                  \
            float4 a0_ = *(const float4*)&x_s[0][d_g * 64 + k4_ * 4];         \
            float4 a1_ = *(const float4*)&x_s[1][d_g * 64 + k4_ * 4];         \
            float4 a2_ = *(const float4*)&x_s[2][d_g * 64 + k4_ * 4];         \
            float4 a3_ = *(const float4*)&x_s[3][d_g * 64 + k4_ * 4];         \
            float w0_ = wih[k4_*4], w1_ = wih[k4_*4+1];                       \
            float w2_ = wih[k4_*4+2], w3_ = wih[k4_*4+3];                     \
            p0_ += w0_*a0_.x + w1_*a0_.y + w2_*a0_.z + w3_*a0_.w;             \
            p1_ += w0_*a1_.x + w1_*a1_.y + w2_*a1_.z + w3_*a1_.w;             \
            p2_ += w0_*a2_.x + w1_*a2_.y + w2_*a2_.z + w3_*a2_.w;             \
            p3_ += w0_*a3_.x + w1_*a3_.y + w2_*a3_.z + w3_*a3_.w;             \
        }                                                                     \
        xpart[d_g][0][jl2] = p0_; xpart[d_g][1][jl2] = p1_;                   \
        xpart[d_g][2][jl2] = p2_; xpart[d_g][3][jl2] = p3_;                   \
        __syncthreads();                                                      \
        xpl[d_g][jl2] = biasR + xpart[0][d_g][jl2] + xpart[1][d_g][jl2]       \
                              + xpart[2][d_g][jl2] + xpart[3][d_g][jl2];      \
        ZXOUT = baR + wax0 * x_s[d_g][0] + wax1 * x_s[d_g][1]                 \
                    + wax2 * x_s[d_g][2];                                     \
    } while (0)

    const int i0 = dir ? kN - 1 : 0;
    float zx_cur, zx_prev = 0.f;
    {
        float4 xv0;
        XLOAD(i0, xv0);
        XFIN(xv0, zx_cur);
    }
    __syncthreads();   // xpl(i0) visible before step 0's cell

    for (int t = 0; t < kN; t++) {
        const int i = dir ? kN - 1 - t : t;
        const int par = t & 1;

        // ---- prefetch next node's edge row ----
        float4 xv_n;
        {
            const int nn = (t + 1 < kN) ? (dir ? i - 1 : i + 1) : i;
            XLOAD(nn, xv_n);
        }

        if (t > 0) {
            const int ipv = dir ? i + 1 : i - 1;        // previous node
            const unsigned stc = (unsigned)t;           // its stamp
            const int parc = (t - 1) & 1;

            // ---- issue batched loads (h first, z rides along) ----
            const ull* hb = hpay + (((size_t)(dir * 2 + parc) * 4) << 9);
            ull hv_[8];
            #pragma unroll
            for (int q = 0; q < 8; q++) hv_[q] = ld_pair(hb + (d_g << 9) + jl2 * 8 + q);
            const ull* zb = zpay + (((size_t)(dir * 2 + parc) * 32) << 8) + tid;
            ull zv_[32];
            #pragma unroll
            for (int bb = 0; bb < 32; bb++) zv_[bb] = ld_pair(zb + ((size_t)bb << 8));

            // ---- resolve h (batched sweeps), stage to LDS ----
            for (;;) {
                bool ok = true;
                #pragma unroll
                for (int q = 0; q < 8; q++) ok &= ((unsigned)(hv_[q] >> 32) == stc);
                if (ok) break;
                #pragma unroll
                for (int q = 0; q < 8; q++)
                    if ((unsigned)(hv_[q] >> 32) != stc)
                        hv_[q] = ld_pair(hb + (d_g << 9) + jl2 * 8 + q);
            }
            #pragma unroll
            for (int q = 0; q < 8; q++) {
                const int k = jl2 * 8 + q;
                ha_p[d_g * 528 + (k >> 7) * 132 + (k & 127)] =
                    __uint_as_float((unsigned)hv_[q]);
            }
            __syncthreads();

            // ---- A': per-arc matvecs Md = h_arc_d . Whh^T (own 64 rows) ----
            #pragma unroll
            for (int d = 0; d < 4; d++) {
                const float* hp = &ha_p[d * 528 + ks * 132];
                float a2 = 0.f;
                #pragma unroll
                for (int kk = 0; kk < 128; kk += 4) {
                    float4 hv4 = *(const float4*)(hp + kk);
                    a2 += w[kk]*hv4.x + w[kk+1]*hv4.y + w[kk+2]*hv4.z + w[kk+3]*hv4.w;
                }
                a2 += __shfl_xor(a2, 1);
                a2 += __shfl_xor(a2, 2);
                if (ks == 0) Mhd[d][jl] = a2;
            }

            // ---- resolve z -> logit(prev) ----
            for (;;) {
                bool ok = true;
                #pragma unroll
                for (int bb = 0; bb < 32; bb++)
                    ok &= ((unsigned)(zv_[bb] >> 32) == stc);
                if (ok) break;
                #pragma unroll
                for (int bb = 0; bb < 32; bb++)
                    if ((unsigned)(zv_[bb] >> 32) != stc)
                        zv_[bb] = ld_pair(zb + ((size_t)bb << 8));
            }
            float zsum = 0.f;
            #pragma unroll
            for (int bb = 0; bb < 32; bb++) zsum += __uint_as_float((unsigned)zv_[bb]);
            float lv = WaoR * fmaxf(zsum + zx_prev, 0.f);
            #pragma unroll
            for (int o2 = 1; o2 < 64; o2 <<= 1) lv += __shfl_xor(lv, o2);
            {
                const int ppv = dir ? ipv + 1 + d_g : ipv - 1 - d_g;
                const bool vp = dir ? (ppv < kN) : (ppv >= 0);
                if (jl2 == 0) logit_l[d_g] = vp ? tanhf(lv + baoR) : -1e9f;
            }
            __syncthreads();   // Mhd + logit_l ready

            // ---- combine: wg(prev) -> M(prev), c_node(prev) ----
            float l0 = logit_l[0], l1 = logit_l[1], l2 = logit_l[2], l3 = logit_l[3];
            float mx = fmaxf(fmaxf(l0, l1), fmaxf(l2, l3));
            float e0 = __expf(l0 - mx), e1 = __expf(l1 - mx);
            float e2 = __expf(l2 - mx), e3 = __expf(l3 - mx);
            float inv = 1.f / (e0 + e1 + e2 + e3);
            float wg0 = e0 * inv, wg1 = e1 * inv, wg2 = e2 * inv, wg3 = e3 * inv;
            if (d_g == 0) {
                Mh[ipv & 3][jl2] = wg0 * Mhd[0][jl2] + wg1 * Mhd[1][jl2]
                                 + wg2 * Mhd[2][jl2] + wg3 * Mhd[3][jl2];
            }
            if (tid < 16) {
                cring[ipv & 3][tid] = wg0 * carcl[0][tid] + wg1 * carcl[1][tid]
                                    + wg2 * carcl[2][tid] + wg3 * carcl[3][tid];
            }
            __syncthreads();   // Mh/cring ready; carcl free to overwrite
        }

        // ---- B: gates + LSTM for node i, publish h_arc slice + z partials ----
        const unsigned stamp = (unsigned)(t + 1);
        const int pp = dir ? i + 1 + d_g : i - 1 - d_g;
        const bool v3 = dir ? (pp < kN) : (pp >= 0);
        if (jl2 < 16) {
            const int s3 = jl2;
            float gi = xpl[d_g][s3]      + Mh[pp & 3][s3];
            float gf = xpl[d_g][16 + s3] + Mh[pp & 3][16 + s3];
            float gg = xpl[d_g][32 + s3] + Mh[pp & 3][32 + s3];
            float go = xpl[d_g][48 + s3] + Mh[pp & 3][48 + s3];
            float cp = cring[pp & 3][s3];
            float c = sigm(gf) * cp + sigm(gi) * tanhf(gg);
            float h = sigm(go) * tanhf(c);
            float hm = v3 ? h : 0.f, cm = v3 ? c : 0.f;
            harcl[d_g][s3] = hm; carcl[d_g][s3] = cm;
            arc[((size_t)i * 4 + d_g) * kH + b * 16 + s3] = __float2bfloat16(hm);
            st_pair(hpay + (((dir * 2 + par) * 4 + d_g) << 9) + b * 16 + s3, hm, stamp);
        }
        {   // z partial over own 16 h-dims (intra-wave harcl dep, no barrier)
            float zp = 0.f;
            #pragma unroll
            for (int ss = 0; ss < 16; ss++) zp += WaS[a_id][ss] * harcl[d_g][ss];
            st_pair(zpay + (((dir * 2 + par) * 32 + b) << 8) + tid, zp, stamp);
        }

        // ---- C: next node's input projection (fills publish-visibility time) ----
        float zx_n;
        XFIN(xv_n, zx_n);
        zx_prev = zx_cur; zx_cur = zx_n;
    }
#undef XLOAD
#undef XFIN
}

// ---------------------------------------------------------------------------
// decoder: out[e] += sum_l Wdo[l] * relu(bd[l] + sum_k Wd[l,k] feat[e,k])
// ---------------------------------------------------------------------------
__global__ __launch_bounds__(256) void k_dec(
    const __hip_bfloat16* __restrict__ arc_f, const __hip_bfloat16* __restrict__ arc_b,
    const float* __restrict__ Wd, const float* __restrict__ bd,
    const float* __restrict__ Wdo, float* __restrict__ out) {
    const int e0 = blockIdx.x * 128;
    const int l0 = blockIdx.y * 128;
    __shared__ __align__(16) float As[8][128];
    __shared__ __align__(16) float Bs[8][128];
    const int tid = threadIdx.x;
    const int tx = tid & 15, ty = tid >> 4;
    const int lr = tid & 127, kq = tid >> 7;

    const int e = e0 + lr;
    const int j = e >> 2, d = e & 3;
    const int jb = j - 1 - d;
    const __hip_bfloat16* frow  = arc_f + (size_t)e * kH;
    const __hip_bfloat16* brow2 = (jb >= 0) ? (arc_b + ((size_t)jb * 4 + d) * kH) : nullptr;
    const float* wrow = Wd + (size_t)(l0 + lr) * (2 * kH);

    float acc[8][8] = {};
    for (int k0 = 0; k0 < 2 * kH; k0 += 8) {
        const int kk = k0 + kq * 4;
        float4 av4;
        if (kk < kH) av4 = ld_bf4(frow + kk);
        else if (brow2) av4 = ld_bf4(brow2 + (kk - kH));
        else av4 = make_float4(0.f, 0.f, 0.f, 0.f);
        float4 bv4 = *(const float4*)(wrow + kk);
        __syncthreads();
        As[kq*4+0][lr] = av4.x; As[kq*4+1][lr] = av4.y;
        As[kq*4+2][lr] = av4.z; As[kq*4+3][lr] = av4.w;
        Bs[kq*4+0][lr] = bv4.x; Bs[kq*4+1][lr] = bv4.y;
        Bs[kq*4+2][lr] = bv4.z; Bs[kq*4+3][lr] = bv4.w;
        __syncthreads();
        #pragma unroll
        for (int kt = 0; kt < 8; kt++) {
            __align__(16) float a0[8], b0[8];
            *(float4*)&a0[0] = *(const float4*)&As[kt][ty*8];
            *(float4*)&a0[4] = *(const float4*)&As[kt][ty*8+4];
            *(float4*)&b0[0] = *(const float4*)&Bs[kt][tx*8];
            *(float4*)&b0[4] = *(const float4*)&Bs[kt][tx*8+4];
            #pragma unroll
            for (int mi = 0; mi < 8; mi++)
                #pragma unroll
                for (int ni = 0; ni < 8; ni++)
                    acc[mi][ni] += a0[mi] * b0[ni];
        }
    }
    #pragma unroll
    for (int mi = 0; mi < 8; mi++) {
        float sacc = 0.f;
        #pragma unroll
        for (int ni = 0; ni < 8; ni++) {
            int l = l0 + tx * 8 + ni;
            sacc += Wdo[l] * fmaxf(acc[mi][ni] + bd[l], 0.f);
        }
        sacc += __shfl_xor(sacc, 1);
        sacc += __shfl_xor(sacc, 2);
        sacc += __shfl_xor(sacc, 4);
        sacc += __shfl_xor(sacc, 8);
        if (tx == 0) atomicAdd(out + e0 + ty * 8 + mi, sacc);
    }
}

// ---------------------------------------------------------------------------
extern "C" void kernel_launch(void* const* d_in, const int* in_sizes, int n_in,
                              void* d_out, int out_size, void* d_ws, size_t ws_size,
                              hipStream_t stream) {
    const float* edges = (const float*)d_in[0];
    const float* Wih_f = (const float*)d_in[1];
    const float* Whh_f = (const float*)d_in[2];
    const float* b_f   = (const float*)d_in[3];
    const float* Wih_b = (const float*)d_in[4];
    const float* Whh_b = (const float*)d_in[5];
    const float* b_b   = (const float*)d_in[6];
    const float* Wa    = (const float*)d_in[7];
    const float* ba    = (const float*)d_in[8];
    const float* Wao   = (const float*)d_in[9];
    const float* bao   = (const float*)d_in[10];
    const float* Wd    = (const float*)d_in[11];
    const float* bd    = (const float*)d_in[12];
    const float* Wdo   = (const float*)d_in[13];
    const float* bdo   = (const float*)d_in[14];
    float* out = (float*)d_out;

    char* ws = (char*)d_ws;
    size_t off = 0;
    __hip_bfloat16* arc_f = (__hip_bfloat16*)(ws + off); off += (size_t)kE * kH * 2;  // 32 MB
    __hip_bfloat16* arc_b = (__hip_bfloat16*)(ws + off); off += (size_t)kE * kH * 2;  // 32 MB
    ull* hpay = (ull*)(ws + off); off += (size_t)2 * 2 * 4 * kH * 8;                  // 64 KB
    ull* zpay = (ull*)(ws + off); off += (size_t)2 * 2 * 32 * 256 * 8;                // 256 KB
    int* claims = (int*)(ws + off); off += 64;

    if (ws_size < off) {
        hipLaunchKernelGGL(k_zero, dim3((kE + 255) / 256), dim3(256), 0, stream, out);
        return;
    }

    hipLaunchKernelGGL(k_init, dim3(128), dim3(256), 0, stream,
                       out, bdo, hpay, zpay, claims);
    hipLaunchKernelGGL(k_recur, dim3(512), dim3(256), 0, stream,
                       edges, Wih_f, Whh_f, b_f, Wih_b, Whh_b, b_b,
                       Wa, ba, Wao, bao, arc_f, arc_b, hpay, zpay, claims);
    hipLaunchKernelGGL(k_dec, dim3(kE / 128, kL / 128), dim3(256), 0, stream,
                       arc_f, arc_b, Wd, bd, Wdo, out);
}